// Round 12
// baseline (1170.751 us; speedup 1.0000x reference)
//
#include <hip/hip_runtime.h>
#include <math.h>

// B=256, N_ROIS=200, ROI_DIM=199, D=192, H=6, Dh=32, L=3, FF=576, NCLS=2
// T = 51200 tokens.
// R0 fences / R3 swizzle / R6-R8 precision ladder (pure-bf16 GEMM+attn,
// absmax at residual-pair floor 2^-16) / R10 one-shot softmax (attn 53us).
// R11 (this): (a) attn PV pair-fencing — chunks 2c/2c+1 into buf0/buf1,
// ONE lgkmcnt fence per pair (7->4 fences/q-tile; WAR across pairs safe
// by in-order DS, same argument as R9's parity scheme). (b) pool KV path
// bf16 (gemm_ns<3> out, attn_pool bf16 in): -78MB HBM round trip.
// (c) 5 conv_wt launches merged into 1 (z-segmented grid).

typedef unsigned short u16;
typedef unsigned int u32;
typedef __attribute__((ext_vector_type(8))) __bf16 bf16x8;
typedef __attribute__((ext_vector_type(4))) float f32x4;

#define GLL16(gp, lp) __builtin_amdgcn_global_load_lds(                 \
    (const __attribute__((address_space(1))) void*)(gp),                \
    (__attribute__((address_space(3))) void*)(lp), 16, 0, 0)

#define FENCE_VM()   do { asm volatile("s_waitcnt vmcnt(0)" ::: "memory");  \
                          __builtin_amdgcn_sched_barrier(0); } while (0)
#define FENCE_LGKM() do { asm volatile("s_waitcnt lgkmcnt(0)" ::: "memory");\
                          __builtin_amdgcn_sched_barrier(0); } while (0)

__device__ __forceinline__ u16 f2bf(float x) {
    u32 u = __float_as_uint(x);
    u = (u + 0x7FFFu + ((u >> 16) & 1u)) >> 16;   // RNE
    return (u16)u;
}
__device__ __forceinline__ float bf2f(u16 h) {
    return __uint_as_float(((u32)h) << 16);
}

__device__ __forceinline__ float gelu_exact(float x) {
    return 0.5f * x * (1.0f + erff(x * 0.7071067811865475f));
}

__device__ __forceinline__ float wave_sum(float v) {
#pragma unroll
    for (int o = 32; o > 0; o >>= 1) v += __shfl_xor(v, o, 64);
    return v;
}
__device__ __forceinline__ float wave_max(float v) {
#pragma unroll
    for (int o = 32; o > 0; o >>= 1) v = fmaxf(v, __shfl_xor(v, o, 64));
    return v;
}
// reduce across the 16 lanes sharing a quad (row of an MFMA C tile)
__device__ __forceinline__ float row_sum16(float v) {
    v += __shfl_xor(v, 1, 64); v += __shfl_xor(v, 2, 64);
    v += __shfl_xor(v, 4, 64); v += __shfl_xor(v, 8, 64);
    return v;
}

__device__ __forceinline__ f32x4 mfma_bf16(bf16x8 a, bf16x8 b, f32x4 c) {
    return __builtin_amdgcn_mfma_f32_16x16x32_bf16(a, b, c, 0, 0, 0);
}

// ---------------------------------------------------------------------------
// Merged weight prep (R11): 5 weight tensors, one launch.
// z-segments: [0,9) Wqkv(192x192) | [9,12) W1(192x576) | [12,15) W2(576x192)
//             | [15,18) Wo(192x192) | [18,20) pool_Wkv(192x192)
// fp32 [K,N] slice -> transposed bf16 [N][K].
// ---------------------------------------------------------------------------
__global__ void conv_wt_all(
    const float* __restrict__ Wqkv, const float* __restrict__ W1,
    const float* __restrict__ W2,   const float* __restrict__ Wo,
    const float* __restrict__ Wkv,
    u16* __restrict__ oqkv, u16* __restrict__ o1, u16* __restrict__ o2,
    u16* __restrict__ oo,   u16* __restrict__ okv)
{
    const int z = blockIdx.z;
    const float* W; u16* o; int K, N, s;
    if (z < 9)       { W = Wqkv; o = oqkv; K = 192; N = 192; s = z; }
    else if (z < 12) { W = W1;   o = o1;   K = 192; N = 576; s = z - 9; }
    else if (z < 15) { W = W2;   o = o2;   K = 576; N = 192; s = z - 12; }
    else if (z < 18) { W = Wo;   o = oo;   K = 192; N = 192; s = z - 15; }
    else             { W = Wkv;  o = okv;  K = 192; N = 192; s = z - 18; }
    const int idx = blockIdx.x * 256 + threadIdx.x;
    if (idx >= K * N) return;
    const int k = idx / N, n = idx - k * N;
    const float x = W[(long)s * K * N + idx];
    o[(long)s * K * N + (long)n * K + k] = f2bf(x);
}

// ---------------------------------------------------------------------------
// x [256][39800] fp32 -> xh [200][256][224] u16 (k>=199 -> 0)
// ---------------------------------------------------------------------------
__global__ void conv_x(const float* __restrict__ x, u16* __restrict__ xh)
{
    const long idx = (long)blockIdx.x * 256 + threadIdx.x;
    if (idx >= 200L * 256 * 224) return;
    const int k = (int)(idx % 224);
    const long t = idx / 224;
    const int m = (int)(t % 256);
    const int z = (int)(t / 256);
    const float v = (k < 199) ? x[(long)m * 39800 + z * 199 + k] : 0.f;
    xh[idx] = f2bf(v);
}

// ---------------------------------------------------------------------------
// roi_W [200][199][192] fp32 -> wth [200][192][224] (LDS-tiled transpose)
// ---------------------------------------------------------------------------
__global__ void conv_roiw(const float* __restrict__ W, u16* __restrict__ oh)
{
    __shared__ float tile[32][33];
    const int z = blockIdx.z;
    const int k0 = blockIdx.x * 32;
    const int n0 = blockIdx.y * 32;
    for (int i = threadIdx.y; i < 32; i += 8) {
        const int k = k0 + i, n = n0 + threadIdx.x;
        tile[i][threadIdx.x] = (k < 199) ? W[((long)z * 199 + k) * 192 + n] : 0.f;
    }
    __syncthreads();
    for (int i = threadIdx.y; i < 32; i += 8) {
        const int n = n0 + i, k = k0 + threadIdx.x;
        const float v = tile[threadIdx.x][i];
        oh[((long)z * 192 + n) * 224 + k] = f2bf(v);
    }
}

// ---------------------------------------------------------------------------
// 2Mx2N pure-bf16 GEMM (EPI 0/2/3): C = Ah * Bh. Tile 128x192, BK=32.
// EPI 0: fp32 C. EPI 2: gelu, bf16 store. EPI 3: plain bf16 store.
// ---------------------------------------------------------------------------
template<int EPI>
__global__ __launch_bounds__(256, 3) void gemm_ns(
    const u16* __restrict__ Ah,
    const u16* __restrict__ Bh,
    const float* __restrict__ bias,
    float* __restrict__ C, u16* __restrict__ Ch,
    int N, int K)
{
    __shared__ u16 Ash[128][32];
    __shared__ u16 Bsh[192][32];

    const int tid = threadIdx.x;
    const int wave = tid >> 6, lane = tid & 63;
    const int lm = lane & 15, quad = lane >> 4;
    const int wm = wave >> 1, wn = wave & 1;
    const long m0 = (long)blockIdx.x * 128;
    const int n0 = blockIdx.y * 192;
    const int lrow = lane >> 2;
    const int lch  = (((lane & 3) ^ (lrow & 3)) * 8);   // staging swizzle
    const int sq   = (quad ^ (lm & 3)) * 8;             // read swizzle

    const u16* pA0h = Ah + (m0 + wave * 32 +  0 + lrow) * K + lch;
    const u16* pA1h = Ah + (m0 + wave * 32 + 16 + lrow) * K + lch;
    const u16* pB0h = Bh + (long)(n0 + wave * 48 +  0 + lrow) * K + lch;
    const u16* pB1h = Bh + (long)(n0 + wave * 48 + 16 + lrow) * K + lch;
    const u16* pB2h = Bh + (long)(n0 + wave * 48 + 32 + lrow) * K + lch;

    auto stage = [&](int k0) {
        GLL16(pA0h + k0, &Ash[wave * 32][0]);
        GLL16(pA1h + k0, &Ash[wave * 32 + 16][0]);
        GLL16(pB0h + k0, &Bsh[wave * 48][0]);
        GLL16(pB1h + k0, &Bsh[wave * 48 + 16][0]);
        GLL16(pB2h + k0, &Bsh[wave * 48 + 32][0]);
    };

    f32x4 acc[4][6];
#pragma unroll
    for (int i = 0; i < 4; i++)
#pragma unroll
        for (int j = 0; j < 6; j++)
#pragma unroll
            for (int r = 0; r < 4; r++) acc[i][j][r] = 0.f;

    const int kt = K >> 5;
    stage(0);
    FENCE_VM();
    __syncthreads();

    for (int t = 0; t < kt; t++) {
        bf16x8 afh[4];
#pragma unroll
        for (int mi = 0; mi < 4; mi++)
            afh[mi] = *(const bf16x8*)&Ash[wm * 64 + mi * 16 + lm][sq];
#pragma unroll
        for (int jh = 0; jh < 2; jh++) {
            bf16x8 bfh[3];
#pragma unroll
            for (int j = 0; j < 3; j++)
                bfh[j] = *(const bf16x8*)&Bsh[wn * 96 + (jh * 3 + j) * 16 + lm][sq];
#pragma unroll
            for (int mi = 0; mi < 4; mi++)
#pragma unroll
                for (int j = 0; j < 3; j++)
                    acc[mi][jh * 3 + j] =
                        mfma_bf16(afh[mi], bfh[j], acc[mi][jh * 3 + j]);
        }
        if (t + 1 < kt) {
            __syncthreads();
            stage((t + 1) << 5);
            FENCE_VM();
            __syncthreads();
        }
    }

#pragma unroll
    for (int mi = 0; mi < 4; mi++) {
        const long rowb = m0 + wm * 64 + mi * 16 + quad * 4;
#pragma unroll
        for (int nj = 0; nj < 6; nj++) {
            const int col = n0 + wn * 96 + nj * 16 + lm;
            const float bv = bias[col];
#pragma unroll
            for (int r = 0; r < 4; r++) {
                float v = acc[mi][nj][r] + bv;
                if (EPI == 0) {
                    C[(rowb + r) * N + col] = v;
                } else {
                    if (EPI == 2) v = gelu_exact(v);
                    Ch[(rowb + r) * N + col] = f2bf(v);
                }
            }
        }
    }
}

// ---------------------------------------------------------------------------
// 4-wave-M pure-bf16 GEMM with fused residual+LN epilogue:
// H := LN(H + acc + bias). N must be 192 (full rows per wave for the LN).
// ---------------------------------------------------------------------------
__global__ __launch_bounds__(256, 3) void gemm_ln(
    const u16* __restrict__ Ah,
    const u16* __restrict__ Bh,
    const float* __restrict__ bias,
    u16* __restrict__ Hh, u16* __restrict__ Hl,
    const float* __restrict__ lng, const float* __restrict__ lnb,
    int K)
{
    __shared__ u16 Ash[128][32];
    __shared__ u16 Bsh[192][32];

    const int tid = threadIdx.x;
    const int wave = tid >> 6, lane = tid & 63;
    const int lm = lane & 15, quad = lane >> 4;
    const long m0 = (long)blockIdx.x * 128;
    const int lrow = lane >> 2;
    const int lch  = (((lane & 3) ^ (lrow & 3)) * 8);
    const int sq   = (quad ^ (lm & 3)) * 8;

    const u16* pA0h = Ah + (m0 + wave * 32 +  0 + lrow) * K + lch;
    const u16* pA1h = Ah + (m0 + wave * 32 + 16 + lrow) * K + lch;
    const u16* pB0h = Bh + (long)(wave * 48 +  0 + lrow) * K + lch;
    const u16* pB1h = Bh + (long)(wave * 48 + 16 + lrow) * K + lch;
    const u16* pB2h = Bh + (long)(wave * 48 + 32 + lrow) * K + lch;

    auto stage = [&](int k0) {
        GLL16(pA0h + k0, &Ash[wave * 32][0]);
        GLL16(pA1h + k0, &Ash[wave * 32 + 16][0]);
        GLL16(pB0h + k0, &Bsh[wave * 48][0]);
        GLL16(pB1h + k0, &Bsh[wave * 48 + 16][0]);
        GLL16(pB2h + k0, &Bsh[wave * 48 + 32][0]);
    };

    f32x4 acc[2][12];
#pragma unroll
    for (int i = 0; i < 2; i++)
#pragma unroll
        for (int j = 0; j < 12; j++)
#pragma unroll
            for (int r = 0; r < 4; r++) acc[i][j][r] = 0.f;

    const int kt = K >> 5;
    stage(0);
    FENCE_VM();
    __syncthreads();

    for (int t = 0; t < kt; t++) {
        bf16x8 afh[2];
#pragma unroll
        for (int mi = 0; mi < 2; mi++)
            afh[mi] = *(const bf16x8*)&Ash[wave * 32 + mi * 16 + lm][sq];
#pragma unroll
        for (int g = 0; g < 4; g++) {
            bf16x8 bfh[3];
#pragma unroll
            for (int j = 0; j < 3; j++)
                bfh[j] = *(const bf16x8*)&Bsh[g * 48 + j * 16 + lm][sq];
#pragma unroll
            for (int mi = 0; mi < 2; mi++)
#pragma unroll
                for (int j = 0; j < 3; j++) {
                    const int ni = g * 3 + j;
                    acc[mi][ni] = mfma_bf16(afh[mi], bfh[j], acc[mi][ni]);
                }
        }
        if (t + 1 < kt) {
            __syncthreads();
            stage((t + 1) << 5);
            FENCE_VM();
            __syncthreads();
        }
    }

    float gv[12], bv2[12], biasv[12];
#pragma unroll
    for (int ni = 0; ni < 12; ni++) {
        const int col = ni * 16 + lm;
        gv[ni] = lng[col]; bv2[ni] = lnb[col]; biasv[ni] = bias[col];
    }
#pragma unroll
    for (int mi = 0; mi < 2; mi++) {
#pragma unroll
        for (int r = 0; r < 4; r++) {
            const long row = m0 + wave * 32 + mi * 16 + quad * 4 + r;
            const long rb = row * 192;
            float vals[12];
            float s = 0.f;
#pragma unroll
            for (int ni = 0; ni < 12; ni++) {
                const int col = ni * 16 + lm;
                const float hval = bf2f(Hh[rb + col]) + bf2f(Hl[rb + col]);
                vals[ni] = acc[mi][ni][r] + biasv[ni] + hval;
                s += vals[ni];
            }
            const float mean = row_sum16(s) * (1.f / 192.f);
            float ss = 0.f;
#pragma unroll
            for (int ni = 0; ni < 12; ni++) {
                vals[ni] -= mean;
                ss += vals[ni] * vals[ni];
            }
            const float var = row_sum16(ss) * (1.f / 192.f);
            const float rsr = 1.f / sqrtf(var + 1e-5f);
#pragma unroll
            for (int ni = 0; ni < 12; ni++) {
                const int col = ni * 16 + lm;
                const float y = vals[ni] * rsr * gv[ni] + bv2[ni];
                const u16 hb = f2bf(y);
                Hh[rb + col] = hb;
                Hl[rb + col] = f2bf(y - bf2f(hb));
            }
        }
    }
}

// ---------------------------------------------------------------------------
// Tokenizer MFMA (pure bf16): per-z GEMM [256,224]@[192,224]^T with fused
// bias+LN+gelu+pos epilogue (full-row LN -> keeps 4-wave-M layout).
// ---------------------------------------------------------------------------
__global__ __launch_bounds__(256, 3) void tok_mfma(
    const u16* __restrict__ xh,
    const u16* __restrict__ wth,
    const float* __restrict__ roi_b,
    const float* __restrict__ lng, const float* __restrict__ lnb,
    const float* __restrict__ pos,
    u16* __restrict__ hh, u16* __restrict__ hl)
{
    __shared__ u16 Ash[128][32];
    __shared__ u16 Bsh[192][32];

    const int tid = threadIdx.x;
    const int wave = tid >> 6, lane = tid & 63;
    const int lm = lane & 15, quad = lane >> 4;
    const int m0 = blockIdx.x * 128;
    const int z = blockIdx.y;
    const int lrow = lane >> 2;
    const int lch  = (((lane & 3) ^ (lrow & 3)) * 8);
    const int sq   = (quad ^ (lm & 3)) * 8;
    const int K = 224;

    const u16* pA0h = xh + ((long)z * 256 + m0 + wave * 32 +  0 + lrow) * K + lch;
    const u16* pA1h = xh + ((long)z * 256 + m0 + wave * 32 + 16 + lrow) * K + lch;
    const u16* pB0h = wth + ((long)z * 192 + wave * 48 +  0 + lrow) * K + lch;
    const u16* pB1h = wth + ((long)z * 192 + wave * 48 + 16 + lrow) * K + lch;
    const u16* pB2h = wth + ((long)z * 192 + wave * 48 + 32 + lrow) * K + lch;

    auto stage = [&](int k0) {
        GLL16(pA0h + k0, &Ash[wave * 32][0]);
        GLL16(pA1h + k0, &Ash[wave * 32 + 16][0]);
        GLL16(pB0h + k0, &Bsh[wave * 48][0]);
        GLL16(pB1h + k0, &Bsh[wave * 48 + 16][0]);
        GLL16(pB2h + k0, &Bsh[wave * 48 + 32][0]);
    };

    f32x4 acc[2][12];
#pragma unroll
    for (int i = 0; i < 2; i++)
#pragma unroll
        for (int j = 0; j < 12; j++)
#pragma unroll
            for (int r = 0; r < 4; r++) acc[i][j][r] = 0.f;

    stage(0);
    FENCE_VM();
    __syncthreads();
    for (int t = 0; t < 7; t++) {
        bf16x8 afh[2];
#pragma unroll
        for (int mi = 0; mi < 2; mi++)
            afh[mi] = *(const bf16x8*)&Ash[wave * 32 + mi * 16 + lm][sq];
#pragma unroll
        for (int g = 0; g < 4; g++) {
            bf16x8 bfh[3];
#pragma unroll
            for (int j = 0; j < 3; j++)
                bfh[j] = *(const bf16x8*)&Bsh[g * 48 + j * 16 + lm][sq];
#pragma unroll
            for (int mi = 0; mi < 2; mi++)
#pragma unroll
                for (int j = 0; j < 3; j++) {
                    const int ni = g * 3 + j;
                    acc[mi][ni] = mfma_bf16(afh[mi], bfh[j], acc[mi][ni]);
                }
        }
        if (t + 1 < 7) {
            __syncthreads();
            stage((t + 1) << 5);
            FENCE_VM();
            __syncthreads();
        }
    }

    float gv[12], bv2[12], biasv[12], pv[12];
#pragma unroll
    for (int ni = 0; ni < 12; ni++) {
        const int col = ni * 16 + lm;
        gv[ni]    = lng[z * 192 + col];
        bv2[ni]   = lnb[z * 192 + col];
        biasv[ni] = roi_b[z * 192 + col];
        pv[ni]    = pos[z * 192 + col];
    }
#pragma unroll
    for (int mi = 0; mi < 2; mi++) {
#pragma unroll
        for (int r = 0; r < 4; r++) {
            const int brow = m0 + wave * 32 + mi * 16 + quad * 4 + r;
            float vals[12];
            float s = 0.f;
#pragma unroll
            for (int ni = 0; ni < 12; ni++) {
                vals[ni] = acc[mi][ni][r] + biasv[ni];
                s += vals[ni];
            }
            const float mean = row_sum16(s) * (1.f / 192.f);
            float ss = 0.f;
#pragma unroll
            for (int ni = 0; ni < 12; ni++) {
                vals[ni] -= mean;
                ss += vals[ni] * vals[ni];
            }
            const float var = row_sum16(ss) * (1.f / 192.f);
            const float rsr = 1.f / sqrtf(var + 1e-5f);
            const long ob = ((long)brow * 200 + z) * 192;
#pragma unroll
            for (int ni = 0; ni < 12; ni++) {
                const int col = ni * 16 + lm;
                const float y = gelu_exact(vals[ni] * rsr * gv[ni] + bv2[ni]) + pv[ni];
                const u16 hb = f2bf(y);
                hh[ob + col] = hb;
                hl[ob + col] = f2bf(y - bf2f(hb));
            }
        }
    }
}

// ---------------------------------------------------------------------------
// fp32 GEMM (tiny pool GEMMs). Tile 128x64, BK=16.
// ---------------------------------------------------------------------------
template<int EPI>
__global__ __launch_bounds__(256) void gemm_kernel(
    const float* __restrict__ A, int lda, long strideA,
    const float* __restrict__ Bw, long strideB,
    const float* __restrict__ bias, long strideBias,
    float* __restrict__ C, int ldc, long strideC,
    int M, int N, int K, int ldb)
{
    __shared__ float As[16][132];
    __shared__ float Bs[16][68];

    const int z = blockIdx.z;
    const float* Ab    = A    + (long)z * strideA;
    const float* Bb    = Bw   + (long)z * strideB;
    const float* biasb = bias + (long)z * strideBias;
    float*       Cb    = C    + (long)z * strideC;

    const int row0 = blockIdx.x * 128;
    const int col0 = blockIdx.y * 64;
    const int tid  = threadIdx.x;
    const int tm = tid >> 4;
    const int tn = tid & 15;

    const int la_m = tid >> 1;
    const int la_k = (tid & 1) * 8;
    const int lb_k = tid >> 4;
    const int lb_n = (tid & 15) * 4;

    const float* bcol = Bb + (col0 + lb_n);
    const float* arow = Ab + (long)(row0 + la_m) * lda;
    const bool vecA = ((lda & 3) == 0) &&
                      ((((unsigned long long)(const void*)arow) & 15ull) == 0ull);

    float acc[8][4];
#pragma unroll
    for (int i = 0; i < 8; i++)
#pragma unroll
        for (int j = 0; j < 4; j++) acc[i][j] = 0.f;

    for (int k0 = 0; k0 < K; k0 += 16) {
        if (vecA && (k0 + 16 <= K)) {
            float4 v0 = *(const float4*)(arow + k0 + la_k);
            float4 v1 = *(const float4*)(arow + k0 + la_k + 4);
            As[la_k + 0][la_m] = v0.x; As[la_k + 1][la_m] = v0.y;
            As[la_k + 2][la_m] = v0.z; As[la_k + 3][la_m] = v0.w;
            As[la_k + 4][la_m] = v1.x; As[la_k + 5][la_m] = v1.y;
            As[la_k + 6][la_m] = v1.z; As[la_k + 7][la_m] = v1.w;
        } else {
#pragma unroll
            for (int i = 0; i < 8; i++) {
                int k = k0 + la_k + i;
                As[la_k + i][la_m] = (k < K) ? arow[k] : 0.f;
            }
        }
        {
            int k = k0 + lb_k;
            float4 v = make_float4(0.f, 0.f, 0.f, 0.f);
            if (k < K) v = *(const float4*)(bcol + (long)k * ldb);
            *(float4*)&Bs[lb_k][lb_n] = v;
        }
        __syncthreads();
#pragma unroll
        for (int kk = 0; kk < 16; kk++) {
            float4 a0 = *(const float4*)&As[kk][tm * 8];
            float4 a1 = *(const float4*)&As[kk][tm * 8 + 4];
            float4 b4 = *(const float4*)&Bs[kk][tn * 4];
            float av[8] = {a0.x, a0.y, a0.z, a0.w, a1.x, a1.y, a1.z, a1.w};
            float bv[4] = {b4.x, b4.y, b4.z, b4.w};
#pragma unroll
            for (int i = 0; i < 8; i++)
#pragma unroll
                for (int j = 0; j < 4; j++) acc[i][j] += av[i] * bv[j];
        }
        __syncthreads();
    }

    const int gcol = col0 + tn * 4;
    float4 bv4 = *(const float4*)(biasb + gcol);
#pragma unroll
    for (int i = 0; i < 8; i++) {
        int grow = row0 + tm * 8 + i;
        float4 o;
        o.x = acc[i][0] + bv4.x; o.y = acc[i][1] + bv4.y;
        o.z = acc[i][2] + bv4.z; o.w = acc[i][3] + bv4.w;
        if (EPI == 1) {
            o.x = gelu_exact(o.x); o.y = gelu_exact(o.y);
            o.z = gelu_exact(o.z); o.w = gelu_exact(o.w);
        }
        *(float4*)(Cb + (long)grow * ldc + gcol) = o;
    }
}

// ---------------------------------------------------------------------------
// MFMA flash encoder attention — one-shot softmax (R10) + R11 pair-fencing:
// PV chunks 2c/2c+1 write buf0/buf1, ONE lgkmcnt fence, read both, 4 MFMAs.
// Fences per q-tile 7->4. WAR across pairs safe: DS in-order per wave
// (write issued after read in program order cannot bypass it).
// LDS = Ksh[208][40] + Vth[32][224] + Pbuf[4][2][16][40] = 41.2 KB.
// ---------------------------------------------------------------------------
__global__ __launch_bounds__(256, 2) void attn_enc_mfma(
    const u16* __restrict__ qkvh, u16* __restrict__ outh)
{
    __shared__ u16 Ksh[208][40];        // 16640 B
    __shared__ u16 Vth[32][224];        // 14336 B
    __shared__ u16 Pbuf[4][2][16][40];  // 10240 B

    const int bh = blockIdx.x;
    const int b = bh / 6, h = bh % 6;
    const int tid = threadIdx.x;
    const int wave = tid >> 6, lane = tid & 63;
    const int lm = lane & 15, quad = lane >> 4;
    const int nq = (wave == 0) ? 4 : 3;

    uint4 qh[4];
#pragma unroll
    for (int i = 0; i < 4; i++) {
        if (i < nq) {
            int qt = wave + 4 * i;
            int qrow = qt * 16 + lm; if (qrow > 199) qrow = 199;
            const long off = (long)(b * 200 + qrow) * 576 + h * 32 + quad * 8;
            qh[i] = *(const uint4*)(qkvh + off);
        }
    }

    // ---- staging (single phase): waves 0-1 -> K, waves 2-3 -> V^T ----
    if (wave < 2) {
        const int sub = wave * 64 + lane;            // 0..127
#pragma unroll
        for (int rep = 0; rep < 7; rep++) {
            const int idx = rep * 128 + sub;
            if (idx < 208 * 4) {
                const int key = idx >> 2, ch = idx & 3;
                const bool valid = key < 200;
                const long roff = (long)(b * 200 + (valid ? key : 0)) * 576
                                  + h * 32 + 192 + ch * 8;
                uint4 v = valid ? *(const uint4*)(qkvh + roff)
                                : make_uint4(0, 0, 0, 0);
                *(uint4*)(&Ksh[0][0] + key * 40 + ch * 8) = v;
            }
        }
    } else {
        const int sub = (wave - 2) * 64 + lane;      // 0..127
#pragma unroll
        for (int rep = 0; rep < 4; rep++) {
            const int idx = rep * 128 + sub;
            if (idx < 224 * 2) {
                const int key = idx >> 1, hf = idx & 1;
                const bool valid = key < 200;
                const long roff = (long)(b * 200 + (valid ? key : 0)) * 576
                                  + h * 32 + 384 + hf * 16;
                uint4 v0 = valid ? *(const uint4*)(qkvh + roff)
                                 : make_uint4(0, 0, 0, 0);
                uint4 v1 = valid ? *(const uint4*)(qkvh + roff + 8)
                                 : make_uint4(0, 0, 0, 0);
                const u16* p0 = (const u16*)&v0;
                const u16* p1 = (const u16*)&v1;
#pragma unroll
                for (int j = 0; j < 8; j++) {
                    Vth[hf * 16 + j][key]     = p0[j];
                    Vth[hf * 16 + 8 + j][key] = p1[j];
                }
            }
        }
    }
    __syncthreads();

    const float scale = 0.17677669529663688f;
    float lrow[4][4];
    f32x4 accO[4][2];

#pragma unroll
    for (int i = 0; i < 4; i++) {
        if (i >= nq) continue;
        const bf16x8 qhf = *(const bf16x8*)&qh[i];
        float s[13][4];
#pragma unroll
        for (int ni = 0; ni < 13; ni++) {
            bf16x8 kh8 = *(const bf16x8*)&Ksh[ni * 16 + lm][quad * 8];
            f32x4 c = {0.f, 0.f, 0.f, 0.f};
            c = mfma_bf16(qhf, kh8, c);
            const bool masked = (ni * 16 + lm) >= 200;
#pragma unroll
            for (int r = 0; r < 4; r++)
                s[ni][r] = masked ? -1e30f : c[r] * scale;
        }
        // one-shot softmax per row
#pragma unroll
        for (int r = 0; r < 4; r++) {
            float pm = s[0][r];
#pragma unroll
            for (int ni = 1; ni < 13; ni++) pm = fmaxf(pm, s[ni][r]);
            pm = fmaxf(pm, __shfl_xor(pm, 1, 64));
            pm = fmaxf(pm, __shfl_xor(pm, 2, 64));
            pm = fmaxf(pm, __shfl_xor(pm, 4, 64));
            pm = fmaxf(pm, __shfl_xor(pm, 8, 64));
            float ps = 0.f;
#pragma unroll
            for (int ni = 0; ni < 13; ni++) {
                float e = __expf(s[ni][r] - pm);
                s[ni][r] = e;
                ps += e;
            }
            ps += __shfl_xor(ps, 1, 64);
            ps += __shfl_xor(ps, 2, 64);
            ps += __shfl_xor(ps, 4, 64);
            ps += __shfl_xor(ps, 8, 64);
            lrow[i][r] = ps;
            accO[i][0][r] = 0.f;
            accO[i][1][r] = 0.f;
        }
        // PV: 7 chunks of 32 keys, pair-fenced through buf0/buf1.
#pragma unroll
        for (int cp = 0; cp < 4; cp++) {
#pragma unroll
            for (int half = 0; half < 2; half++) {
                const int ck = 2 * cp + half;
                if (ck >= 7) continue;
#pragma unroll
                for (int tl = 0; tl < 2; tl++) {
                    const int t = 2 * ck + tl;   // 0..13
#pragma unroll
                    for (int r = 0; r < 4; r++) {
                        const float val = (t < 13) ? s[t][r] : 0.f;
                        Pbuf[wave][half][quad * 4 + r][tl * 16 + lm] = f2bf(val);
                    }
                }
            }
            // RAW guard: one fence per chunk pair.
            FENCE_LGKM();
#pragma unroll
            for (int half = 0; half < 2; half++) {
                const int ck = 2 * cp + half;
                if (ck >= 7) continue;
                const bf16x8 pa = *(const bf16x8*)&Pbuf[wave][half][lm][quad * 8];
#pragma unroll
                for (int nt = 0; nt < 2; nt++) {
                    bf16x8 vh8 = *(const bf16x8*)&Vth[nt * 16 + lm][ck * 32 + quad * 8];
                    accO[i][nt] = mfma_bf16(pa, vh8, accO[i][nt]);
                }
            }
        }
    }

#pragma unroll
    for (int i = 0; i < 4; i++) {
        if (i >= nq) continue;
        const int qt = wave + 4 * i;
#pragma unroll
        for (int r = 0; r < 4; r++) {
            const int qrow = qt * 16 + quad * 4 + r;
            if (qrow >= 200) continue;
            const float inv = 1.f / lrow[i][r];
            const long ob = (long)(b * 200 + qrow) * 192 + h * 32 + lm;
            outh[ob]      = f2bf(accO[i][0][r] * inv);
            outh[ob + 16] = f2bf(accO[i][1][r] * inv);
        }
    }
}

// ---------------------------------------------------------------------------
__global__ __launch_bounds__(192) void mean_tokens_pair(
    const u16* __restrict__ hh, const u16* __restrict__ hl, float* __restrict__ qmean)
{
    const int b = blockIdx.x, d = threadIdx.x;
    float s = 0.f;
    for (int r = 0; r < 200; r++) {
        const long idx = ((long)b * 200 + r) * 192 + d;
        s += bf2f(hh[idx]) + bf2f(hl[idx]);
    }
    qmean[b * 192 + d] = s * (1.f / 200.f);
}

// ---------------------------------------------------------------------------
// attn_pool — R11: kv is bf16 [T,384] (k at h*32, v at 192+h*32).
// ---------------------------------------------------------------------------
__global__ __launch_bounds__(64) void attn_pool(
    const float* __restrict__ qp, const u16* __restrict__ kv,
    float* __restrict__ out)
{
    __shared__ float p[200];
    const int b = blockIdx.x / 6, h = blockIdx.x % 6;
    const int lane = threadIdx.x;

    const float* qrow = qp + b * 192 + h * 32;
    float qr[32];
#pragma unroll
    for (int u = 0; u < 8; u++) {
        float4 t = *(const float4*)(qrow + 4 * u);
        qr[4 * u] = t.x; qr[4 * u + 1] = t.y;
        qr[4 * u + 2] = t.z; qr[4 * u + 3] = t.w;
    }
    const float scale = 0.17677669529663688f;
    const u16* kb = kv + (long)(b * 200) * 384 + h * 32;
    float s[4];
    float mymax = -1e30f;
#pragma unroll
    for (int g = 0; g < 4; g++) {
        int j = lane + 64 * g;
        if (j < 200) {
            const u16* kr = kb + (long)j * 384;
            float acc = 0.f;
#pragma unroll
            for (int u = 0; u < 4; u++) {
                uint4 k8 = *(const uint4*)(kr + 8 * u);
                const u16* kp = (const u16*)&k8;
#pragma unroll
                for (int j2 = 0; j2 < 8; j2++)
                    acc += qr[8 * u + j2] * bf2f(kp[j2]);
            }
            s[g] = acc * scale;
            mymax = fmaxf(mymax, s[g]);
        } else {
            s[g] = -1e30f;
        }
    }
    float mx = wave_max(mymax);
    float psum = 0.f;
#pragma unroll
    for (int g = 0; g < 4; g++) {
        int j = lane + 64 * g;
        if (j < 200) {
            float e = __expf(s[g] - mx);
            p[j] = e;
            psum += e;
        }
    }
    float tot = wave_sum(psum);
    __syncthreads();
    const int half = lane >> 5, d = lane & 31;
    const u16* vb = kv + (long)(b * 200) * 384 + 192 + h * 32 + d;
    float acc = 0.f;
    for (int jj = 0; jj < 100; jj++) {
        int j = half * 100 + jj;
        acc += p[j] * bf2f(vb[(long)j * 384]);
    }
    acc += __shfl_xor(acc, 32, 64);
    acc /= tot;
    if (lane < 32) out[b * 192 + h * 32 + d] = acc;
}

// ---------------------------------------------------------------------------
__global__ __launch_bounds__(64) void classifier_kernel(
    const float* __restrict__ pooled,
    const float* __restrict__ g, const float* __restrict__ bt,
    const float* __restrict__ W1, const float* __restrict__ b1,
    const float* __restrict__ W2, const float* __restrict__ b2,
    const float* __restrict__ W3, const float* __restrict__ b3,
    float* __restrict__ out)
{
    __shared__ float z[192];
    __shared__ float z1[96];
    __shared__ float z2[48];
    const int b = blockIdx.x, lane = threadIdx.x;
    const float* pr = pooled + b * 192;
    float x0 = pr[lane], x1 = pr[lane + 64], x2 = pr[lane + 128];
    float m = wave_sum(x0 + x1 + x2) * (1.f / 192.f);
    float d0 = x0 - m, d1 = x1 - m, d2 = x2 - m;
    float v = wave_sum(d0 * d0 + d1 * d1 + d2 * d2) * (1.f / 192.f);
    float rs = 1.f / sqrtf(v + 1e-5f);
    z[lane]       = d0 * rs * g[lane]       + bt[lane];
    z[lane + 64]  = d1 * rs * g[lane + 64]  + bt[lane + 64];
    z[lane + 128] = d2 * rs * g[lane + 128] + bt[lane + 128];
    __syncthreads();
#pragma unroll
    for (int rep = 0; rep < 2; rep++) {
        int j = lane + rep * 64;
        if (j < 96) {
            float a = b1[j];
            for (int k = 0; k < 192; k++) a += z[k] * W1[k * 96 + j];
            z1[j] = gelu_exact(a);
        }
    }
    __syncthreads();
    if (lane < 48) {
        float a = b2[lane];
        for (int k = 0; k < 96; k++) a += z1[k] * W2[k * 48 + lane];
        z2[lane] = gelu_exact(a);
    }
    __syncthreads();
    if (lane < 2) {
        float a = b3[lane];
        for (int k = 0; k < 48; k++) a += z2[k] * W3[k * 2 + lane];
        out[b * 2 + lane] = a;
    }
}

// ---------------------------------------------------------------------------
extern "C" void kernel_launch(void* const* d_in, const int* in_sizes, int n_in,
                              void* d_out, int out_size, void* d_ws, size_t ws_size,
                              hipStream_t stream)
{
    (void)in_sizes; (void)n_in; (void)out_size; (void)ws_size;

    const float* x         = (const float*)d_in[0];
    const float* roi_W     = (const float*)d_in[1];
    const float* roi_b     = (const float*)d_in[2];
    const float* roi_ln_g  = (const float*)d_in[3];
    const float* roi_ln_b  = (const float*)d_in[4];
    const float* pos_emb   = (const float*)d_in[5];
    const float* enc_Wqkv  = (const float*)d_in[6];
    const float* enc_bqkv  = (const float*)d_in[7];
    const float* enc_Wo    = (const float*)d_in[8];
    const float* enc_bo    = (const float*)d_in[9];
    const float* enc_ln1_g = (const float*)d_in[10];
    const float* enc_ln1_b = (const float*)d_in[11];
    const float* enc_W1    = (const float*)d_in[12];
    const float* enc_b1    = (const float*)d_in[13];
    const float* enc_W2    = (const float*)d_in[14];
    const float* enc_b2    = (const float*)d_in[15];
    const float* enc_ln2_g = (const float*)d_in[16];
    const float* enc_ln2_b = (const float*)d_in[17];
    const float* pool_Wqkv = (const float*)d_in[18];
    const float* pool_bqkv = (const float*)d_in[19];
    const float* pool_Wo   = (const float*)d_in[20];
    const float* pool_bo   = (const float*)d_in[21];
    const float* cls_ln_g  = (const float*)d_in[22];
    const float* cls_ln_b  = (const float*)d_in[23];
    const float* cls_W1    = (const float*)d_in[24];
    const float* cls_b1    = (const float*)d_in[25];
    const float* cls_W2    = (const float*)d_in[26];
    const float* cls_b2    = (const float*)d_in[27];
    const float* cls_W3    = (const float*)d_in[28];
    const float* cls_b3    = (const float*)d_in[29];

    char* ws = (char*)d_ws;
    u16*   hh    = (u16*)(ws);                      // [T,192] hi
    u16*   hl    = (u16*)(ws + 19660800);           // [T,192] lo
    char*  bufA  = ws + 39321600;                   // 117,964,800 B
    // tokenizer-phase layout of bufA:
    u16*   xh    = (u16*)bufA;                      // 200*256*224 u16
    u16*   wth   = (u16*)(bufA + 45875200);         // 200*192*224 u16
    // encoder-phase layout of bufA:
    u16*   qkvh  = (u16*)bufA;                      // [T,576] hi (single plane)
    u16*   ffh   = (u16*)bufA;                      // [T,576] (hi only)
    u16*   kvb   = (u16*)bufA;                      // pool KV bf16 [T,384]
    char*  bufB  = ws + 157286400;
    u16*   bBh   = (u16*)bufB;                      // attn out (hi only)
    float* qmean = (float*)(ws + 196608000);
    float* qp    = qmean + 49152;
    float* pattn = qp + 49152;
    float* pooled= pattn + 49152;
    char*  wts   = ws + 197394432;
    u16* WqkvH = (u16*)(wts);
    u16* Wff1H = (u16*)(wts + 1327104);
    u16* Wff2H = (u16*)(wts + 2654208);
    u16* WwoH  = (u16*)(wts + 3981312);
    u16* WkvH  = (u16*)(wts + 4423680);

    // ---- weight split/transpose: ONE launch (R11) ----
    conv_wt_all<<<dim3(432, 1, 20), 256, 0, stream>>>(
        enc_Wqkv, enc_W1, enc_W2, enc_Wo, pool_Wqkv + 36864,
        WqkvH, Wff1H, Wff2H, WwoH, WkvH);

    // ---- tokenizer ----
    conv_x<<<44800, 256, 0, stream>>>(x, xh);
    conv_roiw<<<dim3(7, 6, 200), dim3(32, 8), 0, stream>>>(roi_W, wth);
    tok_mfma<<<dim3(2, 200), 256, 0, stream>>>(
        xh, wth, roi_b, roi_ln_g, roi_ln_b, pos_emb, hh, hl);

    // ---- encoder layers ----
    for (int i = 0; i < 3; i++) {
        gemm_ns<3><<<dim3(400, 3), 256, 0, stream>>>(
            hh, WqkvH + (long)i * 110592,
            enc_bqkv + i * 576, nullptr, qkvh, 576, 192);
        attn_enc_mfma<<<1536, 256, 0, stream>>>(qkvh, bBh);
        gemm_ln<<<dim3(400, 1), 256, 0, stream>>>(
            bBh, WwoH + (long)i * 36864,
            enc_bo + i * 192,
            hh, hl, enc_ln1_g + i * 192, enc_ln1_b + i * 192, 192);
        gemm_ns<2><<<dim3(400, 3), 256, 0, stream>>>(
            hh, Wff1H + (long)i * 110592,
            enc_b1 + i * 576, nullptr, ffh, 576, 192);
        gemm_ln<<<dim3(400, 1), 256, 0, stream>>>(
            ffh, Wff2H + (long)i * 110592,
            enc_b2 + i * 192,
            hh, hl, enc_ln2_g + i * 192, enc_ln2_b + i * 192, 576);
    }

    // ---- pooling ----
    mean_tokens_pair<<<256, 192, 0, stream>>>(hh, hl, qmean);
    gemm_kernel<0><<<dim3(2, 3, 1), 256, 0, stream>>>(
        qmean, 192, 0, pool_Wqkv, 0, pool_bqkv, 0, qp, 192, 0, 256, 192, 192, 192);
    gemm_ns<3><<<dim3(400, 2), 256, 0, stream>>>(
        hh, WkvH, pool_bqkv + 192, nullptr, kvb, 384, 192);
    attn_pool<<<1536, 64, 0, stream>>>(qp, kvb, pattn);
    gemm_kernel<0><<<dim3(2, 3, 1), 256, 0, stream>>>(
        pattn, 192, 0, pool_Wo, 0, pool_bo, 0, pooled, 192, 0, 256, 192, 192, 192);

    // ---- classifier ----
    classifier_kernel<<<256, 64, 0, stream>>>(
        pooled, cls_ln_g, cls_ln_b,
        cls_W1, cls_b1, cls_W2, cls_b2, cls_W3, cls_b3,
        (float*)d_out);
}